// Round 25
// baseline (134.370 us; speedup 1.0000x reference)
//
#include <hip/hip_runtime.h>
#include <math.h>

// Problem constants
//  B=8, C_IN=80, T=1000, D_MODEL=256, D_STATE=16, DT_RANK=16,
//  D_CONV=4, N_LABELS=35, D_INNER=512

// ---- workspace layout (float offsets) ----
#define OFF_W1T    0         // [80][1024]  folded (in_proj@proj) transposed
#define OFF_B1     81920     // [1024]      folded bias
#define OFF_W2S    82944     // [35][512]   (fc_w@out_proj_w) * 1e-3 (mean fold)
#define OFF_AL2    100864    // [512][16]   A = -exp(A_log)
#define OFF_XH     109056    // [8000][512] silu(conv(xh)) — live through k3
#define OFF_SZ     4205056   // [8000][512] silu(z)       — live through k3
#define OFF_CHUNKA 8301056   // [20ck][8b][16s][512d] float4 (P,q,S1,S2) = 5,242,880 floats
#define OFF_ACC20  13543936  // [20ck][8b][512d] xh*sz partials = 81,920 floats
#define OFF_DBCP   13625856  // [4ks][8000][48] k2b partials (PERMUTED rows) = 1,536,000 floats
#define OFF_YBAR   18878976  // [8][512]
#define WS_FLOATS  18883072  // ~75.5 MB

#define CK_FLOATS 262144
#define CHUNK_BASE(ck) (OFF_CHUNKA + (ck) * CK_FLOATS)
#define K3_NT 50             // 20 chunks x 50 t = 1000 — compile-time trip count

__device__ __forceinline__ float silu_f(float v) {
  return v / (1.f + __expf(-v));
}

// ================= prep (merged): W1T fold (320 blocks) + small tables =====
__global__ __launch_bounds__(256) void prep_all(const float* __restrict__ proj_w,
                                                const float* __restrict__ proj_b,
                                                const float* __restrict__ in_proj_w,
                                                const float* __restrict__ fc_w,
                                                const float* __restrict__ out_proj_w,
                                                const float* __restrict__ A_log,
                                                float* __restrict__ ws) {
  const int tid = threadIdx.x;
  if (blockIdx.x < 320) {
    // W1T[c][n] = sum_m in_proj_w[n][m] * proj_w[m][c]; tile = 8 c x 32 n
    const int nt = blockIdx.x / 10;     // 32 tiles of 32 n
    const int ct = blockIdx.x % 10;     // 10 tiles of 8 c
    const int n0 = nt * 32, c0 = ct * 8;
    __shared__ float Pl[8 * 68];        // [c][k]
    __shared__ float Il[64 * 36];       // [k][n]
    const int ng = tid & 31, cg = tid >> 5;   // one output per thread
    float acc = 0.f;
    for (int kc = 0; kc < 256; kc += 64) {
      __syncthreads();
      for (int i = tid; i < 8 * 64; i += 256) {
        int k = i >> 3, c = i & 7;
        Pl[c * 68 + k] = proj_w[(kc + k) * 80 + c0 + c];
      }
      for (int i = tid; i < 32 * 64; i += 256) {
        int n = i >> 6, k = i & 63;
        Il[k * 36 + n] = in_proj_w[(n0 + n) * 256 + kc + k];
      }
      __syncthreads();
#pragma unroll 8
      for (int k = 0; k < 64; ++k)
        acc = fmaf(Pl[cg * 68 + k], Il[k * 36 + ng], acc);
    }
    ws[OFF_W1T + (c0 + cg) * 1024 + n0 + ng] = acc;
  } else {
    int idx = (blockIdx.x - 320) * 256 + tid;
    if (idx < 1024) {
      float s = 0.f;
      for (int m = 0; m < 256; ++m) s = fmaf(in_proj_w[idx * 256 + m], proj_b[m], s);
      ws[OFF_B1 + idx] = s;
    } else if (idx < 1024 + 17920) {
      int j = idx - 1024;
      int n = j / 512, d = j - n * 512;
      float s = 0.f;
      for (int m = 0; m < 256; ++m) s = fmaf(fc_w[n * 256 + m], out_proj_w[m * 512 + d], s);
      ws[OFF_W2S + j] = s * 1e-3f;      // fold mean over T=1000
    } else if (idx < 1024 + 17920 + 8192) {
      int j = idx - (1024 + 17920);
      ws[OFF_AL2 + j] = -expf(A_log[j]);
    }
  }
}

// ================= K1: xz = X @ W1T + b1, DUAL-PIPE x delivery =============
// (r22 form, ~45us — parked.)
template <bool EDGE>
__device__ __forceinline__ void k1_body(const float* __restrict__ x,
                                        const float* __restrict__ xs,
                                        const float* __restrict__ conv_w,
                                        const float* __restrict__ conv_b,
                                        float* __restrict__ ws,
                                        int nt, int tch, int b) {
  const int tid = threadIdx.x;
  const int n = nt * 256 + tid;        // global n column (0..1023)
  const int t0 = tch * 16;
  const int tbase = t0 - 4;            // acc[j] = xz at t = tbase + j

  float acc[20];
  {
    const float b1v = ws[OFF_B1 + n];
#pragma unroll
    for (int j = 0; j < 20; ++j) acc[j] = b1v;
  }

  const float* __restrict__ w1t = ws + OFF_W1T;
  for (int kc = 0; kc < 80; kc += 8) {
    float wreg[8];
#pragma unroll
    for (int kk = 0; kk < 8; ++kk)
      wreg[kk] = w1t[(kc + kk) * 1024 + n];          // per-lane coalesced
#pragma unroll
    for (int kk = 0; kk < 8; ++kk) {
      const float w = wreg[kk];
      const float* xrl = &xs[(kc + kk) * 20];                       // LDS path
      const float* xrg = x + (b * 80 + kc + kk) * 1000 + tbase;     // SMEM path
#pragma unroll
      for (int g = 0; g < 5; ++g) {
        float4 xv;
        if (EDGE || (kk & 1) == 0)
          xv = *(const float4*)(xrl + g * 4);        // ds_read_b128 broadcast
        else
          xv = *(const float4*)(xrg + g * 4);        // uniform -> s_load_dwordx4
        acc[g * 4 + 0] = fmaf(xv.x, w, acc[g * 4 + 0]);
        acc[g * 4 + 1] = fmaf(xv.y, w, acc[g * 4 + 1]);
        acc[g * 4 + 2] = fmaf(xv.z, w, acc[g * 4 + 2]);
        acc[g * 4 + 3] = fmaf(xv.w, w, acc[g * 4 + 3]);
      }
    }
  }

  if (tch == 0) {
    // reference pads the PROJECTED sequence with zeros: xz[t<0] = 0
    acc[0] = 0.f; acc[1] = 0.f; acc[2] = 0.f; acc[3] = 0.f;
  }

  if (nt < 2) {
    // h-half: causal conv (taps t-3..t) + silu
    const int d = n;
    const float4 cw = *(const float4*)&conv_w[d * 4];
    const float cb = conv_b[d];
#pragma unroll
    for (int i = 0; i < 16; ++i) {
      int t = t0 + i;
      if (t < 1000) {
        float v = cb;
        v = fmaf(cw.x, acc[i + 1], v);   // xz[t-3]
        v = fmaf(cw.y, acc[i + 2], v);   // xz[t-2]
        v = fmaf(cw.z, acc[i + 3], v);   // xz[t-1]
        v = fmaf(cw.w, acc[i + 4], v);   // xz[t]
        ws[OFF_XH + (b * 1000 + t) * 512 + d] = silu_f(v);
      }
    }
  } else {
    const int d0 = n - 512;
#pragma unroll
    for (int i = 0; i < 16; ++i) {
      int t = t0 + i;
      if (t < 1000)
        ws[OFF_SZ + (b * 1000 + t) * 512 + d0] = silu_f(acc[i + 4]);
    }
  }
}

__global__ __launch_bounds__(256) void k1_xz(const float* __restrict__ x,
                                             const float* __restrict__ conv_w,
                                             const float* __restrict__ conv_b,
                                             float* __restrict__ ws) {
  const int nt  = blockIdx.x;   // 4 tiles of 256 n (0,1: conv half; 2,3: z)
  const int tch = blockIdx.y;   // 63 chunks of 16 t
  const int b   = blockIdx.z;
  const int tid = threadIdx.x;
  const int tbase = tch * 16 - 4;

  __shared__ __align__(16) float xs[80 * 20];
  for (int i = tid; i < 1600; i += 256) {
    int k = i / 20, j = i - k * 20;
    int t = tbase + j;
    float v = 0.f;
    if (t >= 0 && t < 1000) v = x[(b * 80 + k) * 1000 + t];
    xs[i] = v;
  }
  __syncthreads();

  if (tch == 0 || tch == 62)
    k1_body<true >(x, xs, conv_w, conv_b, ws, nt, tch, b);
  else
    k1_body<false>(x, xs, conv_w, conv_b, ws, nt, tch, b);
}

// ================= K2b: dbc partials = xh @ x_proj_w.T (split-K x4) =========
// r25: rows written in PERMUTED layout [dt(16) | B0,B1,C0,C1, B2,B3,C2,C3 ..]
// so k3's per-iteration B/C access becomes ONE aligned ds_read_b128 instead
// of two ds_read_b64. Store index computed per output; everything else is
// the proven r17/r21 staged form.
__global__ __launch_bounds__(256) void k2b_dbc(const float* __restrict__ x_proj_w,
                                               float* __restrict__ ws) {
  const int row0 = blockIdx.x * 16;
  const int ks   = blockIdx.y;          // K quarter
  const int k0   = ks * 128;
  __shared__ float Xl[16 * 68];
  __shared__ float Wl[48 * 68];
  const int tid = threadIdx.x;
  const int ng = tid & 15, rg = tid >> 4;
  float acc[3] = {0.f, 0.f, 0.f};
  for (int kc = 0; kc < 128; kc += 64) {
    __syncthreads();
    for (int i = tid; i < 16 * 64; i += 256) {
      int r = i >> 6, c = i & 63;
      Xl[r * 68 + c] = ws[OFF_XH + (row0 + r) * 512 + k0 + kc + c];
    }
    for (int i = tid; i < 48 * 64; i += 256) {
      int r = i >> 6, c = i & 63;
      Wl[r * 68 + c] = x_proj_w[r * 512 + k0 + kc + c];
    }
    __syncthreads();
    for (int c = 0; c < 64; c += 4) {
      float4 xa = *(const float4*)&Xl[rg * 68 + c];
      float4 w0 = *(const float4*)&Wl[(ng * 3 + 0) * 68 + c];
      float4 w1 = *(const float4*)&Wl[(ng * 3 + 1) * 68 + c];
      float4 w2 = *(const float4*)&Wl[(ng * 3 + 2) * 68 + c];
      acc[0] += xa.x*w0.x + xa.y*w0.y + xa.z*w0.z + xa.w*w0.w;
      acc[1] += xa.x*w1.x + xa.y*w1.y + xa.z*w1.z + xa.w*w1.w;
      acc[2] += xa.x*w2.x + xa.y*w2.y + xa.z*w2.z + xa.w*w2.w;
    }
  }
  for (int n = 0; n < 3; ++n) {
    int g = ng * 3 + n;
    int dst;
    if (g < 16)      dst = g;                                   // dt band
    else if (g < 32) { int i = g - 16; dst = 16 + ((i >> 1) << 2) + (i & 1); }     // B
    else             { int i = g - 32; dst = 18 + ((i >> 1) << 2) + (i & 1); }     // C
    ws[OFF_DBCP + ks * 384000 + (row0 + rg) * 48 + dst] = acc[n];
  }
}

// ================= K3: fused delta + scan (r17 form + b128 B/C reads) ======
// block 512 = 64 d-lanes x 8 waves; TWO s-chains/thread (s = wv*2+{0,1}).
// grid (8 dg, 20 ck, 8 b) = 1280 blocks x 8 waves = 40 waves/CU.
// Staging sums the 4 k2b partials via float4 (600 dwordx4-slots); the
// permutation commutes with the sum. Delta phase reads only dt band (<16),
// unchanged. Main loop: ONE ds_read_b128 gives (B0,B1,C0,C1) for this wv.
__global__ __launch_bounds__(512) void k3_scan1(const float* __restrict__ dt_proj_w,
                                                const float* __restrict__ dt_proj_b,
                                                float* __restrict__ ws) {
  const int dg = blockIdx.x;          // 8 groups of 64 d
  const int ck = blockIdx.y;          // 20 chunks of 50 t
  const int b  = blockIdx.z;
  const int tid = threadIdx.x;
  const int lane = tid & 63;
  const int wv = tid >> 6;
  const int d = dg * 64 + lane;
  const int rowbase = b * 1000 + ck * K3_NT;

  __shared__ __align__(16) float dbcl[K3_NT * 48];  // [t][dt(16)|BC-interleaved(32)]
  __shared__ float dlt[K3_NT * 64];                 // [t][d-lane] delta
  {
    const float4* __restrict__ p0 = (const float4*)(ws + OFF_DBCP + rowbase * 48);
    const float4* __restrict__ p1 = (const float4*)(ws + OFF_DBCP + 384000 + rowbase * 48);
    const float4* __restrict__ p2 = (const float4*)(ws + OFF_DBCP + 768000 + rowbase * 48);
    const float4* __restrict__ p3 = (const float4*)(ws + OFF_DBCP + 1152000 + rowbase * 48);
    float4* __restrict__ dst = (float4*)dbcl;
    for (int i = tid; i < K3_NT * 12; i += 512) {   // 600 float4 slots
      float4 a = p0[i], q = p1[i], c = p2[i], e = p3[i];
      dst[i] = make_float4((a.x + q.x) + (c.x + e.x),
                           (a.y + q.y) + (c.y + e.y),
                           (a.z + q.z) + (c.z + e.z),
                           (a.w + q.w) + (c.w + e.w));
    }
  }
  __syncthreads();

  {
    const float4* wp = (const float4*)(dt_proj_w + d * 16);
    const float4 w0 = wp[0], w1 = wp[1], w2 = wp[2], w3 = wp[3];
    const float bias = dt_proj_b[d];
    for (int tt = wv; tt < K3_NT; tt += 8) {        // wave-strided
      const float* dr = &dbcl[tt * 48];
      float4 q0 = *(const float4*)(dr + 0);         // b128 broadcasts (dt band)
      float4 q1 = *(const float4*)(dr + 4);
      float4 q2 = *(const float4*)(dr + 8);
      float4 q3 = *(const float4*)(dr + 12);
      float lin = bias;
      lin = fmaf(q0.x, w0.x, lin); lin = fmaf(q0.y, w0.y, lin);
      lin = fmaf(q0.z, w0.z, lin); lin = fmaf(q0.w, w0.w, lin);
      lin = fmaf(q1.x, w1.x, lin); lin = fmaf(q1.y, w1.y, lin);
      lin = fmaf(q1.z, w1.z, lin); lin = fmaf(q1.w, w1.w, lin);
      lin = fmaf(q2.x, w2.x, lin); lin = fmaf(q2.y, w2.y, lin);
      lin = fmaf(q2.z, w2.z, lin); lin = fmaf(q2.w, w2.w, lin);
      lin = fmaf(q3.x, w3.x, lin); lin = fmaf(q3.y, w3.y, lin);
      lin = fmaf(q3.z, w3.z, lin); lin = fmaf(q3.w, w3.w, lin);
      dlt[tt * 64 + lane] = fmaxf(lin, 0.f) + log1pf(__expf(-fabsf(lin)));
    }
  }
  __syncthreads();

  const float2 av = *(const float2*)&ws[OFF_AL2 + d * 16 + wv * 2];
  const float a0 = av.x, a1 = av.y;
  const float* __restrict__ xhp = ws + OFF_XH + rowbase * 512 + d;
  const float* __restrict__ szp = ws + OFF_SZ + rowbase * 512 + d;
  float h0 = 0.f, h1 = 0.f, cp0 = 1.f, cp1 = 1.f;
  float S10 = 0.f, S11 = 0.f, S20 = 0.f, S21 = 0.f, xacc = 0.f;
#pragma unroll 5
  for (int i = 0; i < K3_NT; ++i) {                 // STATIC bound
    float del = dlt[i * 64 + lane];
    float xh  = xhp[i * 512];
    float sz  = szp[i * 512];
    float4 bc = *(const float4*)&dbcl[i * 48 + 16 + wv * 4];  // (B0,B1,C0,C1) b128
    float du = del * xh;
    xacc = fmaf(xh, sz, xacc);
    float e0 = __expf(del * a0), e1 = __expf(del * a1);
    cp0 *= e0; cp1 *= e1;
    h0 = fmaf(e0, h0, du * bc.x);
    h1 = fmaf(e1, h1, du * bc.y);
    float cs0 = bc.z * sz, cs1 = bc.w * sz;
    S10 = fmaf(h0, cs0, S10); S11 = fmaf(h1, cs1, S11);
    S20 = fmaf(cp0, cs0, S20); S21 = fmaf(cp1, cs1, S21);
  }
  {
    const int cbase = CHUNK_BASE(ck);
    const int s = wv * 2;
    int idx = (b * 16 + s) * 512 + d;
    *(float4*)&ws[cbase + idx * 4] = make_float4(cp0, h0, S10, S20);
    *(float4*)&ws[cbase + (idx + 512) * 4] = make_float4(cp1, h1, S11, S21);
  }
  if (wv == 0) ws[OFF_ACC20 + (ck * 8 + b) * 512 + d] = xacc;
}

// ================= K4: combine 20 chunks (register-prefetched) -> ybar ======
__global__ __launch_bounds__(256, 2) void k4_scan2(const float* __restrict__ Dvec,
                                                   float* __restrict__ ws) {
  const int dg = blockIdx.x;   // 32 groups of 16 d
  const int b  = blockIdx.y;
  const int tid = threadIdx.x;
  const int dl = tid & 15, s = tid >> 4;
  const int d = dg * 16 + dl;
  const int lane = tid & 63, wv = tid >> 6;
  float4 f[20];
#pragma unroll
  for (int k = 0; k < 20; ++k)
    f[k] = *(const float4*)&ws[CHUNK_BASE(k) + ((b * 16 + s) * 512 + d) * 4];
  float h = 0.f, y = 0.f;
#pragma unroll
  for (int k = 0; k < 20; ++k) {
    y = fmaf(f[k].w, h, y + f[k].z);   // S1 + S2*h_in
    h = fmaf(f[k].x, h, f[k].y);       // P*h_in + q
  }
  y += __shfl_xor(y, 16);
  y += __shfl_xor(y, 32);
  __shared__ float ys[4][16];
  if (lane < 16) ys[wv][dl] = y;
  __syncthreads();
  if (tid < 16) {
    float yt = ys[0][tid] + ys[1][tid] + ys[2][tid] + ys[3][tid];
    float acc = 0.f;
#pragma unroll
    for (int k = 0; k < 20; ++k) acc += ws[OFF_ACC20 + (k * 8 + b) * 512 + dg * 16 + tid];
    int dd = dg * 16 + tid;
    ws[OFF_YBAR + b * 512 + dd] = yt + Dvec[dd] * acc;
  }
}

// ================= K5: out = ybar @ W2s.T + fc_b =================
__global__ __launch_bounds__(64) void k5_out(const float* __restrict__ fc_b,
                                             const float* __restrict__ ws,
                                             float* __restrict__ out) {
  const int b = blockIdx.x;
  const int n = threadIdx.x;
  if (n >= 35) return;
  const float* yb = ws + OFF_YBAR + b * 512;
  const float* w  = ws + OFF_W2S + n * 512;
  float sum = 0.f;
#pragma unroll 8
  for (int k = 0; k < 512; ++k) sum = fmaf(yb[k], w[k], sum);
  out[b * 35 + n] = sum + fc_b[n];
}

extern "C" void kernel_launch(void* const* d_in, const int* in_sizes, int n_in,
                              void* d_out, int out_size, void* d_ws, size_t ws_size,
                              hipStream_t stream) {
  const float* x          = (const float*)d_in[0];
  const float* proj_w     = (const float*)d_in[1];
  const float* proj_b     = (const float*)d_in[2];
  const float* in_proj_w  = (const float*)d_in[3];
  const float* conv_w     = (const float*)d_in[4];
  const float* conv_b     = (const float*)d_in[5];
  const float* x_proj_w   = (const float*)d_in[6];
  const float* dt_proj_w  = (const float*)d_in[7];
  const float* dt_proj_b  = (const float*)d_in[8];
  const float* A_log      = (const float*)d_in[9];
  const float* Dvec       = (const float*)d_in[10];
  const float* out_proj_w = (const float*)d_in[11];
  const float* fc_w       = (const float*)d_in[12];
  const float* fc_b       = (const float*)d_in[13];
  float* ws  = (float*)d_ws;
  float* out = (float*)d_out;
  if (ws_size < (size_t)WS_FLOATS * sizeof(float)) return;  // need ~76 MB scratch

  prep_all  <<<426,             256, 0, stream>>>(proj_w, proj_b, in_proj_w, fc_w,
                                                  out_proj_w, A_log, ws);
  k1_xz     <<<dim3(4, 63, 8),  256, 0, stream>>>(x, conv_w, conv_b, ws);
  k2b_dbc   <<<dim3(500, 4),    256, 0, stream>>>(x_proj_w, ws);
  k3_scan1  <<<dim3(8, 20, 8),  512, 0, stream>>>(dt_proj_w, dt_proj_b, ws);
  k4_scan2  <<<dim3(32, 8),     256, 0, stream>>>(Dvec, ws);
  k5_out    <<<8,               64,  0, stream>>>(fc_b, ws, out);
}

// Round 26
// 132.325 us; speedup vs baseline: 1.0155x; 1.0155x over previous
//
#include <hip/hip_runtime.h>
#include <math.h>

// Problem constants
//  B=8, C_IN=80, T=1000, D_MODEL=256, D_STATE=16, DT_RANK=16,
//  D_CONV=4, N_LABELS=35, D_INNER=512

// ---- workspace layout (float offsets) ----
#define OFF_W1T    0         // [80][1024]  folded (in_proj@proj) transposed
#define OFF_B1     81920     // [1024]      folded bias
#define OFF_W2S    82944     // [35][512]   (fc_w@out_proj_w) * 1e-3 (mean fold)
#define OFF_AL2    100864    // [512][16]   A = -exp(A_log)
#define OFF_XH     109056    // [8000][512] silu(conv(xh)) — live through k3
#define OFF_SZ     4205056   // [8000][512] silu(z)       — live through k3
#define OFF_CHUNKA 8301056   // [20ck][8b][16s][512d] float4 (P,q,S1,S2) = 5,242,880 floats
#define OFF_ACC20  13543936  // [20ck][8b][512d] xh*sz partials = 81,920 floats
#define OFF_DBCP   13625856  // [4ks][8000][48] k2b partials = 1,536,000 floats
#define OFF_YBAR   18878976  // [8][512]
#define WS_FLOATS  18883072  // ~75.5 MB

#define CK_FLOATS 262144
#define CHUNK_BASE(ck) (OFF_CHUNKA + (ck) * CK_FLOATS)
#define K3_NT 50             // 20 chunks x 50 t = 1000 — compile-time trip count

__device__ __forceinline__ float silu_f(float v) {
  return v / (1.f + __expf(-v));
}

// ================= prep (merged): W1T fold (320 blocks) + small tables =====
__global__ __launch_bounds__(256) void prep_all(const float* __restrict__ proj_w,
                                                const float* __restrict__ proj_b,
                                                const float* __restrict__ in_proj_w,
                                                const float* __restrict__ fc_w,
                                                const float* __restrict__ out_proj_w,
                                                const float* __restrict__ A_log,
                                                float* __restrict__ ws) {
  const int tid = threadIdx.x;
  if (blockIdx.x < 320) {
    // W1T[c][n] = sum_m in_proj_w[n][m] * proj_w[m][c]; tile = 8 c x 32 n
    const int nt = blockIdx.x / 10;     // 32 tiles of 32 n
    const int ct = blockIdx.x % 10;     // 10 tiles of 8 c
    const int n0 = nt * 32, c0 = ct * 8;
    __shared__ float Pl[8 * 68];        // [c][k]
    __shared__ float Il[64 * 36];       // [k][n]
    const int ng = tid & 31, cg = tid >> 5;   // one output per thread
    float acc = 0.f;
    for (int kc = 0; kc < 256; kc += 64) {
      __syncthreads();
      for (int i = tid; i < 8 * 64; i += 256) {
        int k = i >> 3, c = i & 7;
        Pl[c * 68 + k] = proj_w[(kc + k) * 80 + c0 + c];
      }
      for (int i = tid; i < 32 * 64; i += 256) {
        int n = i >> 6, k = i & 63;
        Il[k * 36 + n] = in_proj_w[(n0 + n) * 256 + kc + k];
      }
      __syncthreads();
#pragma unroll 8
      for (int k = 0; k < 64; ++k)
        acc = fmaf(Pl[cg * 68 + k], Il[k * 36 + ng], acc);
    }
    ws[OFF_W1T + (c0 + cg) * 1024 + n0 + ng] = acc;
  } else {
    int idx = (blockIdx.x - 320) * 256 + tid;
    if (idx < 1024) {
      float s = 0.f;
      for (int m = 0; m < 256; ++m) s = fmaf(in_proj_w[idx * 256 + m], proj_b[m], s);
      ws[OFF_B1 + idx] = s;
    } else if (idx < 1024 + 17920) {
      int j = idx - 1024;
      int n = j / 512, d = j - n * 512;
      float s = 0.f;
      for (int m = 0; m < 256; ++m) s = fmaf(fc_w[n * 256 + m], out_proj_w[m * 512 + d], s);
      ws[OFF_W2S + j] = s * 1e-3f;      // fold mean over T=1000
    } else if (idx < 1024 + 17920 + 8192) {
      int j = idx - (1024 + 17920);
      ws[OFF_AL2 + j] = -expf(A_log[j]);
    }
  }
}

// ================= K1: xz = X @ W1T + b1, DUAL-PIPE x delivery =============
// (r22 form, ~45us — parked.)
template <bool EDGE>
__device__ __forceinline__ void k1_body(const float* __restrict__ x,
                                        const float* __restrict__ xs,
                                        const float* __restrict__ conv_w,
                                        const float* __restrict__ conv_b,
                                        float* __restrict__ ws,
                                        int nt, int tch, int b) {
  const int tid = threadIdx.x;
  const int n = nt * 256 + tid;        // global n column (0..1023)
  const int t0 = tch * 16;
  const int tbase = t0 - 4;            // acc[j] = xz at t = tbase + j

  float acc[20];
  {
    const float b1v = ws[OFF_B1 + n];
#pragma unroll
    for (int j = 0; j < 20; ++j) acc[j] = b1v;
  }

  const float* __restrict__ w1t = ws + OFF_W1T;
  for (int kc = 0; kc < 80; kc += 8) {
    float wreg[8];
#pragma unroll
    for (int kk = 0; kk < 8; ++kk)
      wreg[kk] = w1t[(kc + kk) * 1024 + n];          // per-lane coalesced
#pragma unroll
    for (int kk = 0; kk < 8; ++kk) {
      const float w = wreg[kk];
      const float* xrl = &xs[(kc + kk) * 20];                       // LDS path
      const float* xrg = x + (b * 80 + kc + kk) * 1000 + tbase;     // SMEM path
#pragma unroll
      for (int g = 0; g < 5; ++g) {
        float4 xv;
        if (EDGE || (kk & 1) == 0)
          xv = *(const float4*)(xrl + g * 4);        // ds_read_b128 broadcast
        else
          xv = *(const float4*)(xrg + g * 4);        // uniform -> s_load_dwordx4
        acc[g * 4 + 0] = fmaf(xv.x, w, acc[g * 4 + 0]);
        acc[g * 4 + 1] = fmaf(xv.y, w, acc[g * 4 + 1]);
        acc[g * 4 + 2] = fmaf(xv.z, w, acc[g * 4 + 2]);
        acc[g * 4 + 3] = fmaf(xv.w, w, acc[g * 4 + 3]);
      }
    }
  }

  if (tch == 0) {
    // reference pads the PROJECTED sequence with zeros: xz[t<0] = 0
    acc[0] = 0.f; acc[1] = 0.f; acc[2] = 0.f; acc[3] = 0.f;
  }

  if (nt < 2) {
    // h-half: causal conv (taps t-3..t) + silu
    const int d = n;
    const float4 cw = *(const float4*)&conv_w[d * 4];
    const float cb = conv_b[d];
#pragma unroll
    for (int i = 0; i < 16; ++i) {
      int t = t0 + i;
      if (t < 1000) {
        float v = cb;
        v = fmaf(cw.x, acc[i + 1], v);   // xz[t-3]
        v = fmaf(cw.y, acc[i + 2], v);   // xz[t-2]
        v = fmaf(cw.z, acc[i + 3], v);   // xz[t-1]
        v = fmaf(cw.w, acc[i + 4], v);   // xz[t]
        ws[OFF_XH + (b * 1000 + t) * 512 + d] = silu_f(v);
      }
    }
  } else {
    const int d0 = n - 512;
#pragma unroll
    for (int i = 0; i < 16; ++i) {
      int t = t0 + i;
      if (t < 1000)
        ws[OFF_SZ + (b * 1000 + t) * 512 + d0] = silu_f(acc[i + 4]);
    }
  }
}

__global__ __launch_bounds__(256) void k1_xz(const float* __restrict__ x,
                                             const float* __restrict__ conv_w,
                                             const float* __restrict__ conv_b,
                                             float* __restrict__ ws) {
  const int nt  = blockIdx.x;   // 4 tiles of 256 n (0,1: conv half; 2,3: z)
  const int tch = blockIdx.y;   // 63 chunks of 16 t
  const int b   = blockIdx.z;
  const int tid = threadIdx.x;
  const int tbase = tch * 16 - 4;

  __shared__ __align__(16) float xs[80 * 20];
  for (int i = tid; i < 1600; i += 256) {
    int k = i / 20, j = i - k * 20;
    int t = tbase + j;
    float v = 0.f;
    if (t >= 0 && t < 1000) v = x[(b * 80 + k) * 1000 + t];
    xs[i] = v;
  }
  __syncthreads();

  if (tch == 0 || tch == 62)
    k1_body<true >(x, xs, conv_w, conv_b, ws, nt, tch, b);
  else
    k1_body<false>(x, xs, conv_w, conv_b, ws, nt, tch, b);
}

// ================= K2b: dbc partials = xh @ x_proj_w.T (split-K x4) =========
// LDS-staged both operands (r17/r21 proven form). Direct-global W reads are
// a 16-way per-lane scatter (r23: 91us) — staging is the correct trade.
__global__ __launch_bounds__(256) void k2b_dbc(const float* __restrict__ x_proj_w,
                                               float* __restrict__ ws) {
  const int row0 = blockIdx.x * 16;
  const int ks   = blockIdx.y;          // K quarter
  const int k0   = ks * 128;
  __shared__ float Xl[16 * 68];
  __shared__ float Wl[48 * 68];
  const int tid = threadIdx.x;
  const int ng = tid & 15, rg = tid >> 4;
  float acc[3] = {0.f, 0.f, 0.f};
  for (int kc = 0; kc < 128; kc += 64) {
    __syncthreads();
    for (int i = tid; i < 16 * 64; i += 256) {
      int r = i >> 6, c = i & 63;
      Xl[r * 68 + c] = ws[OFF_XH + (row0 + r) * 512 + k0 + kc + c];
    }
    for (int i = tid; i < 48 * 64; i += 256) {
      int r = i >> 6, c = i & 63;
      Wl[r * 68 + c] = x_proj_w[r * 512 + k0 + kc + c];
    }
    __syncthreads();
    for (int c = 0; c < 64; c += 4) {
      float4 xa = *(const float4*)&Xl[rg * 68 + c];
      float4 w0 = *(const float4*)&Wl[(ng * 3 + 0) * 68 + c];
      float4 w1 = *(const float4*)&Wl[(ng * 3 + 1) * 68 + c];
      float4 w2 = *(const float4*)&Wl[(ng * 3 + 2) * 68 + c];
      acc[0] += xa.x*w0.x + xa.y*w0.y + xa.z*w0.z + xa.w*w0.w;
      acc[1] += xa.x*w1.x + xa.y*w1.y + xa.z*w1.z + xa.w*w1.w;
      acc[2] += xa.x*w2.x + xa.y*w2.y + xa.z*w2.z + xa.w*w2.w;
    }
  }
  for (int n = 0; n < 3; ++n)
    ws[OFF_DBCP + ks * 384000 + (row0 + rg) * 48 + ng * 3 + n] = acc[n];
}

// ================= K3: fused delta + scan (r17 form, float4 staging) =======
// block 512 = 64 d-lanes x 8 waves; TWO s-chains/thread (s = wv*2+{0,1}).
// grid (8 dg, 20 ck, 8 b) = 1280 blocks x 8 waves = 40 waves/CU.
// Staging sums the 4 k2b partials via float4 (600 dwordx4-slots).
__global__ __launch_bounds__(512) void k3_scan1(const float* __restrict__ dt_proj_w,
                                                const float* __restrict__ dt_proj_b,
                                                float* __restrict__ ws) {
  const int dg = blockIdx.x;          // 8 groups of 64 d
  const int ck = blockIdx.y;          // 20 chunks of 50 t
  const int b  = blockIdx.z;
  const int tid = threadIdx.x;
  const int lane = tid & 63;
  const int wv = tid >> 6;
  const int d = dg * 64 + lane;
  const int rowbase = b * 1000 + ck * K3_NT;

  __shared__ __align__(16) float dbcl[K3_NT * 48];  // [t][dt(16)|B(16)|C(16)]
  __shared__ float dlt[K3_NT * 64];                 // [t][d-lane] delta
  {
    const float4* __restrict__ p0 = (const float4*)(ws + OFF_DBCP + rowbase * 48);
    const float4* __restrict__ p1 = (const float4*)(ws + OFF_DBCP + 384000 + rowbase * 48);
    const float4* __restrict__ p2 = (const float4*)(ws + OFF_DBCP + 768000 + rowbase * 48);
    const float4* __restrict__ p3 = (const float4*)(ws + OFF_DBCP + 1152000 + rowbase * 48);
    float4* __restrict__ dst = (float4*)dbcl;
    for (int i = tid; i < K3_NT * 12; i += 512) {   // 600 float4 slots
      float4 a = p0[i], q = p1[i], c = p2[i], e = p3[i];
      dst[i] = make_float4((a.x + q.x) + (c.x + e.x),
                           (a.y + q.y) + (c.y + e.y),
                           (a.z + q.z) + (c.z + e.z),
                           (a.w + q.w) + (c.w + e.w));
    }
  }
  __syncthreads();

  {
    const float4* wp = (const float4*)(dt_proj_w + d * 16);
    const float4 w0 = wp[0], w1 = wp[1], w2 = wp[2], w3 = wp[3];
    const float bias = dt_proj_b[d];
    for (int tt = wv; tt < K3_NT; tt += 8) {        // wave-strided
      const float* dr = &dbcl[tt * 48];
      float4 q0 = *(const float4*)(dr + 0);         // b128 broadcasts
      float4 q1 = *(const float4*)(dr + 4);
      float4 q2 = *(const float4*)(dr + 8);
      float4 q3 = *(const float4*)(dr + 12);
      float lin = bias;
      lin = fmaf(q0.x, w0.x, lin); lin = fmaf(q0.y, w0.y, lin);
      lin = fmaf(q0.z, w0.z, lin); lin = fmaf(q0.w, w0.w, lin);
      lin = fmaf(q1.x, w1.x, lin); lin = fmaf(q1.y, w1.y, lin);
      lin = fmaf(q1.z, w1.z, lin); lin = fmaf(q1.w, w1.w, lin);
      lin = fmaf(q2.x, w2.x, lin); lin = fmaf(q2.y, w2.y, lin);
      lin = fmaf(q2.z, w2.z, lin); lin = fmaf(q2.w, w2.w, lin);
      lin = fmaf(q3.x, w3.x, lin); lin = fmaf(q3.y, w3.y, lin);
      lin = fmaf(q3.z, w3.z, lin); lin = fmaf(q3.w, w3.w, lin);
      dlt[tt * 64 + lane] = fmaxf(lin, 0.f) + log1pf(__expf(-fabsf(lin)));
    }
  }
  __syncthreads();

  const float2 av = *(const float2*)&ws[OFF_AL2 + d * 16 + wv * 2];
  const float a0 = av.x, a1 = av.y;
  const float* __restrict__ xhp = ws + OFF_XH + rowbase * 512 + d;
  const float* __restrict__ szp = ws + OFF_SZ + rowbase * 512 + d;
  float h0 = 0.f, h1 = 0.f, cp0 = 1.f, cp1 = 1.f;
  float S10 = 0.f, S11 = 0.f, S20 = 0.f, S21 = 0.f, xacc = 0.f;
#pragma unroll 5
  for (int i = 0; i < K3_NT; ++i) {                 // STATIC bound
    float del = dlt[i * 64 + lane];
    float xh  = xhp[i * 512];
    float sz  = szp[i * 512];
    float2 bB = *(const float2*)&dbcl[i * 48 + 16 + wv * 2];
    float2 bC = *(const float2*)&dbcl[i * 48 + 32 + wv * 2];
    float du = del * xh;
    xacc = fmaf(xh, sz, xacc);
    float e0 = __expf(del * a0), e1 = __expf(del * a1);
    cp0 *= e0; cp1 *= e1;
    h0 = fmaf(e0, h0, du * bB.x);
    h1 = fmaf(e1, h1, du * bB.y);
    float cs0 = bC.x * sz, cs1 = bC.y * sz;
    S10 = fmaf(h0, cs0, S10); S11 = fmaf(h1, cs1, S11);
    S20 = fmaf(cp0, cs0, S20); S21 = fmaf(cp1, cs1, S21);
  }
  {
    const int cbase = CHUNK_BASE(ck);
    const int s = wv * 2;
    int idx = (b * 16 + s) * 512 + d;
    *(float4*)&ws[cbase + idx * 4] = make_float4(cp0, h0, S10, S20);
    *(float4*)&ws[cbase + (idx + 512) * 4] = make_float4(cp1, h1, S11, S21);
  }
  if (wv == 0) ws[OFF_ACC20 + (ck * 8 + b) * 512 + d] = xacc;
}

// ================= K4: combine 20 chunks (register-prefetched) -> ybar ======
__global__ __launch_bounds__(256, 2) void k4_scan2(const float* __restrict__ Dvec,
                                                   float* __restrict__ ws) {
  const int dg = blockIdx.x;   // 32 groups of 16 d
  const int b  = blockIdx.y;
  const int tid = threadIdx.x;
  const int dl = tid & 15, s = tid >> 4;
  const int d = dg * 16 + dl;
  const int lane = tid & 63, wv = tid >> 6;
  float4 f[20];
#pragma unroll
  for (int k = 0; k < 20; ++k)
    f[k] = *(const float4*)&ws[CHUNK_BASE(k) + ((b * 16 + s) * 512 + d) * 4];
  float h = 0.f, y = 0.f;
#pragma unroll
  for (int k = 0; k < 20; ++k) {
    y = fmaf(f[k].w, h, y + f[k].z);   // S1 + S2*h_in
    h = fmaf(f[k].x, h, f[k].y);       // P*h_in + q
  }
  y += __shfl_xor(y, 16);
  y += __shfl_xor(y, 32);
  __shared__ float ys[4][16];
  if (lane < 16) ys[wv][dl] = y;
  __syncthreads();
  if (tid < 16) {
    float yt = ys[0][tid] + ys[1][tid] + ys[2][tid] + ys[3][tid];
    float acc = 0.f;
#pragma unroll
    for (int k = 0; k < 20; ++k) acc += ws[OFF_ACC20 + (k * 8 + b) * 512 + dg * 16 + tid];
    int dd = dg * 16 + tid;
    ws[OFF_YBAR + b * 512 + dd] = yt + Dvec[dd] * acc;
  }
}

// ================= K5: out = ybar @ W2s.T + fc_b =================
__global__ __launch_bounds__(64) void k5_out(const float* __restrict__ fc_b,
                                             const float* __restrict__ ws,
                                             float* __restrict__ out) {
  const int b = blockIdx.x;
  const int n = threadIdx.x;
  if (n >= 35) return;
  const float* yb = ws + OFF_YBAR + b * 512;
  const float* w  = ws + OFF_W2S + n * 512;
  float sum = 0.f;
#pragma unroll 8
  for (int k = 0; k < 512; ++k) sum = fmaf(yb[k], w[k], sum);
  out[b * 35 + n] = sum + fc_b[n];
}

extern "C" void kernel_launch(void* const* d_in, const int* in_sizes, int n_in,
                              void* d_out, int out_size, void* d_ws, size_t ws_size,
                              hipStream_t stream) {
  const float* x          = (const float*)d_in[0];
  const float* proj_w     = (const float*)d_in[1];
  const float* proj_b     = (const float*)d_in[2];
  const float* in_proj_w  = (const float*)d_in[3];
  const float* conv_w     = (const float*)d_in[4];
  const float* conv_b     = (const float*)d_in[5];
  const float* x_proj_w   = (const float*)d_in[6];
  const float* dt_proj_w  = (const float*)d_in[7];
  const float* dt_proj_b  = (const float*)d_in[8];
  const float* A_log      = (const float*)d_in[9];
  const float* Dvec       = (const float*)d_in[10];
  const float* out_proj_w = (const float*)d_in[11];
  const float* fc_w       = (const float*)d_in[12];
  const float* fc_b       = (const float*)d_in[13];
  float* ws  = (float*)d_ws;
  float* out = (float*)d_out;
  if (ws_size < (size_t)WS_FLOATS * sizeof(float)) return;  // need ~76 MB scratch

  prep_all  <<<426,             256, 0, stream>>>(proj_w, proj_b, in_proj_w, fc_w,
                                                  out_proj_w, A_log, ws);
  k1_xz     <<<dim3(4, 63, 8),  256, 0, stream>>>(x, conv_w, conv_b, ws);
  k2b_dbc   <<<dim3(500, 4),    256, 0, stream>>>(x_proj_w, ws);
  k3_scan1  <<<dim3(8, 20, 8),  512, 0, stream>>>(dt_proj_w, dt_proj_b, ws);
  k4_scan2  <<<dim3(32, 8),     256, 0, stream>>>(Dvec, ws);
  k5_out    <<<8,               64,  0, stream>>>(fc_b, ws, out);
}